// Round 6
// baseline (100.733 us; speedup 1.0000x reference)
//
#include <hip/hip_runtime.h>
#include <stdint.h>

// IndexedLinearLayer = dense bf16 GEMM after two cheap precompute passes:
//   A'[q][b][i] = x[b,i] * [idx[b,i]==q]   (bf16, row-padded to 1040)
//   Bt[o][k]    = table[k][o]              (bf16, k = q*1024+i)
//   parts[q]    = A'[q] @ Bt^T (per 32-batch tile), then reduce + bias.
//
// R6 change vs R4/R5: dropped __builtin_amdgcn_global_load_lds staging
// (two consecutive container deaths on that source, R0-R3 sources all ran;
// the builtin wrapper is the only construct unique to the dying kernel).
// A-tile staging is now a plain coalesced uint4 copy — staging is <1% of
// the GEMM block's work (66 KB vs 2 MB B-stream), so nothing is lost.
//
// R4 rationale: R3's K-loop was request-rate/VALU-bound — 16 scalar fp32 B
// loads + 24 pack-VALU per kb per thread, 256 MB B + 128 MB x/idx L2 traffic.
// Precomputing bf16 A'/Bt once makes the hot loop 2 ds_read_b128 + 2 global
// dwordx4 + 4 MFMA, and drops L2 traffic to ~128 MB B + 17 MB A'.

constexpr int SIZE_IN  = 1024;
constexpr int SIZE_OUT = 256;
constexpr int BATCH    = 512;
constexpr int NUM_Q    = 16;
constexpr int KTOT     = NUM_Q * SIZE_IN;   // 16384
constexpr int A_LD     = 1040;              // bf16 elems/row: +16 pad -> bank shift 8/row
constexpr int TM       = 32;                // batch tile in gemm

// ws layout (bytes), all 16B-aligned
constexpr size_t A_OFF    = 0;
constexpr size_t A_BYTES  = (size_t)NUM_Q * BATCH * A_LD * 2;       // 17,039,360
constexpr size_t BT_OFF   = A_OFF + A_BYTES;
constexpr size_t BT_BYTES = (size_t)SIZE_OUT * KTOT * 2;            //  8,388,608
constexpr size_t P_OFF    = BT_OFF + BT_BYTES;
constexpr size_t P_BYTES  = (size_t)NUM_Q * BATCH * SIZE_OUT * 4;   //  8,388,608
constexpr size_t WS_NEED  = P_OFF + P_BYTES;                        // ~33.8 MB

typedef short short8   __attribute__((ext_vector_type(8)));
typedef float floatx4  __attribute__((ext_vector_type(4)));

__device__ inline uint32_t pack2bf(float lo, float hi) {
    uint32_t a = __float_as_uint(lo) + 0x8000u;
    uint32_t b = __float_as_uint(hi) + 0x8000u;
    return __builtin_amdgcn_perm(b, a, 0x07060302);  // {b.hi16, a.hi16}
}
__device__ inline uint16_t bf1(float f) {
    return (uint16_t)((__float_as_uint(f) + 0x8000u) >> 16);
}

// ---- K0: expand masked x into A'[q][b][A_LD] bf16 (pad cols never read) ----
__global__ __launch_bounds__(256)
void expand_a(const float* __restrict__ x, const int* __restrict__ idx,
              uint16_t* __restrict__ A)
{
    const int g  = blockIdx.x * 256 + threadIdx.x;   // 512 b * 128 i-chunks
    const int b  = g >> 7;
    const int i0 = (g & 127) * 8;
    const float4 xv0 = *(const float4*)(x + b * SIZE_IN + i0);
    const float4 xv1 = *(const float4*)(x + b * SIZE_IN + i0 + 4);
    const int4   iv0 = *(const int4*)(idx + b * SIZE_IN + i0);
    const int4   iv1 = *(const int4*)(idx + b * SIZE_IN + i0 + 4);
    const float xs[8] = {xv0.x,xv0.y,xv0.z,xv0.w, xv1.x,xv1.y,xv1.z,xv1.w};
    const int   is[8] = {iv0.x,iv0.y,iv0.z,iv0.w, iv1.x,iv1.y,iv1.z,iv1.w};
    #pragma unroll
    for (int q = 0; q < NUM_Q; ++q) {
        float m[8];
        #pragma unroll
        for (int j = 0; j < 8; ++j) m[j] = (is[j] == q) ? xs[j] : 0.f;
        uint4 d;
        d.x = pack2bf(m[0], m[1]); d.y = pack2bf(m[2], m[3]);
        d.z = pack2bf(m[4], m[5]); d.w = pack2bf(m[6], m[7]);
        *(uint4*)(A + (size_t)(q * BATCH + b) * A_LD + i0) = d;
    }
}

// ---- K1: Bt[o][k] = bf16(table[k][o]), 64x64 tiles through LDS ----
__global__ __launch_bounds__(256)
void transpose_bt(const float* __restrict__ table, uint16_t* __restrict__ Bt)
{
    __shared__ uint16_t t[64][72];                   // +8 pad
    const int k0  = (blockIdx.x & 255) * 64;
    const int o0  = (blockIdx.x >> 8) * 64;
    const int tid = threadIdx.x;
    {
        const int kr = tid >> 4;                     // 0..15
        const int oc = (tid & 15) * 4;
        #pragma unroll
        for (int rr = 0; rr < 4; ++rr) {
            const int k = rr * 16 + kr;
            const float4 v = *(const float4*)(table + (size_t)(k0 + k) * SIZE_OUT + o0 + oc);
            t[oc + 0][k] = bf1(v.x);
            t[oc + 1][k] = bf1(v.y);
            t[oc + 2][k] = bf1(v.z);
            t[oc + 3][k] = bf1(v.w);
        }
    }
    __syncthreads();
    const int orow = tid >> 2;                       // 0..63
    const int kc   = (tid & 3) * 16;
    const uint4 lo = *(const uint4*)(&t[orow][kc]);
    const uint4 hi = *(const uint4*)(&t[orow][kc + 8]);
    uint16_t* dst = Bt + (size_t)(o0 + orow) * KTOT + k0 + kc;
    *(uint4*)dst       = lo;
    *(uint4*)(dst + 8) = hi;
}

// ---- K2: split-q GEMM. Block = (bt, q); 512 thr = 8 waves, wave owns 32 cols ----
__global__ __launch_bounds__(512, 1)
void gemm_splitq(const uint16_t* __restrict__ A,    // [16*512][A_LD]
                 const uint16_t* __restrict__ Bt,   // [256][16384]
                 float* __restrict__ parts)         // [16][512][256]
{
    __shared__ uint16_t Al[TM * A_LD];              // 66,560 B
    const int tid   = threadIdx.x;
    const int q     = blockIdx.x & 15;              // XCD = blockIdx%8 = q%8
    const int bt    = blockIdx.x >> 4;
    const int b0    = bt * TM;
    const int w     = tid >> 6;
    const int lane  = tid & 63;
    const int nlane = lane & 15;
    const int quad  = lane >> 4;

    // Stage A-tile: plain coalesced uint4 copy of one contiguous 66,560 B
    // region (4160 16B-words; 512 threads -> 8 full sweeps + 64-thread tail).
    {
        const uint4* src = (const uint4*)(A + (size_t)(q * BATCH + b0) * A_LD);
        uint4* dst = (uint4*)Al;
        #pragma unroll
        for (int c = 0; c < 8; ++c)
            dst[c * 512 + tid] = src[c * 512 + tid];
        if (tid < 64) dst[8 * 512 + tid] = src[8 * 512 + tid];
    }
    __syncthreads();

    const uint16_t* bp0 = Bt + (size_t)(w * 32 + nlane) * KTOT + q * SIZE_IN + quad * 8;
    const uint16_t* bp1 = bp0 + (size_t)16 * KTOT;
    const uint16_t* ar0 = Al + nlane * A_LD + quad * 8;
    const uint16_t* ar1 = ar0 + 16 * A_LD;

    floatx4 acc00 = {0,0,0,0}, acc01 = {0,0,0,0}, acc10 = {0,0,0,0}, acc11 = {0,0,0,0};

    #pragma unroll 8
    for (int kb = 0; kb < 32; ++kb) {
        const short8 a0 = *(const short8*)(ar0 + kb * 32);   // ds_read_b128
        const short8 a1 = *(const short8*)(ar1 + kb * 32);
        const short8 bq0 = *(const short8*)(bp0 + kb * 32);  // global dwordx4
        const short8 bq1 = *(const short8*)(bp1 + kb * 32);
        acc00 = __builtin_amdgcn_mfma_f32_16x16x32_bf16(a0, bq0, acc00, 0, 0, 0);
        acc10 = __builtin_amdgcn_mfma_f32_16x16x32_bf16(a1, bq0, acc10, 0, 0, 0);
        acc01 = __builtin_amdgcn_mfma_f32_16x16x32_bf16(a0, bq1, acc01, 0, 0, 0);
        acc11 = __builtin_amdgcn_mfma_f32_16x16x32_bf16(a1, bq1, acc11, 0, 0, 0);
    }

    // C/D layout: col = lane&15, row = quad*4 + reg
    float* pq = parts + ((size_t)q * BATCH + b0) * SIZE_OUT;
    const int col0 = w * 32 + nlane;
    #pragma unroll
    for (int rr = 0; rr < 4; ++rr) {
        const int r0 = quad * 4 + rr;
        pq[(size_t)r0 * SIZE_OUT + col0]            = acc00[rr];
        pq[(size_t)r0 * SIZE_OUT + col0 + 16]       = acc01[rr];
        pq[(size_t)(r0 + 16) * SIZE_OUT + col0]     = acc10[rr];
        pq[(size_t)(r0 + 16) * SIZE_OUT + col0 + 16]= acc11[rr];
    }
}

// ---- K3: sum 16 q-partials + bias ----
__global__ __launch_bounds__(256)
void reduce_ws(const float* __restrict__ ws, const float* __restrict__ bias,
               float* __restrict__ out)
{
    const int e  = blockIdx.x * 256 + threadIdx.x;      // 0..32767 float4s
    const int o4 = e & 63;
    const float4* w4 = reinterpret_cast<const float4*>(ws);
    float4 s = reinterpret_cast<const float4*>(bias)[o4];
    #pragma unroll
    for (int q = 0; q < NUM_Q; ++q) {
        const float4 v = w4[(size_t)q * (BATCH * SIZE_OUT / 4) + e];
        s.x += v.x; s.y += v.y; s.z += v.z; s.w += v.w;
    }
    reinterpret_cast<float4*>(out)[e] = s;
}

// ---- Fallback (ws too small): simple per-row gather (known-correct) ----
__global__ __launch_bounds__(256)
void fallback_gather(const float* __restrict__ x, const int* __restrict__ idx,
                     const float* __restrict__ table, const float* __restrict__ bias,
                     float* __restrict__ out)
{
    __shared__ int2 xr[SIZE_IN];
    const int b = blockIdx.x, tid = threadIdx.x;
    const float4 xv = reinterpret_cast<const float4*>(x + b * SIZE_IN)[tid];
    const int4   qv = reinterpret_cast<const int4*>(idx + b * SIZE_IN)[tid];
    const int ib = tid * 4;
    xr[ib+0] = make_int2(__float_as_int(xv.x), (qv.x*SIZE_IN+ib+0)*SIZE_OUT);
    xr[ib+1] = make_int2(__float_as_int(xv.y), (qv.y*SIZE_IN+ib+1)*SIZE_OUT);
    xr[ib+2] = make_int2(__float_as_int(xv.z), (qv.z*SIZE_IN+ib+2)*SIZE_OUT);
    xr[ib+3] = make_int2(__float_as_int(xv.w), (qv.w*SIZE_IN+ib+3)*SIZE_OUT);
    __syncthreads();
    float s = bias[tid];
    for (int j = 0; j < SIZE_IN; ++j) {
        const int2 p = xr[j];
        s = fmaf(__int_as_float(p.x), table[p.y + tid], s);
    }
    out[b * SIZE_OUT + tid] = s;
}

extern "C" void kernel_launch(void* const* d_in, const int* in_sizes, int n_in,
                              void* d_out, int out_size, void* d_ws, size_t ws_size,
                              hipStream_t stream) {
    const float* x     = (const float*)d_in[0];
    const int*   idx   = (const int*)d_in[1];
    const float* table = (const float*)d_in[2];
    const float* bias  = (const float*)d_in[3];
    float*       out   = (float*)d_out;

    if (ws_size >= WS_NEED) {
        uint16_t* Aws = (uint16_t*)((char*)d_ws + A_OFF);
        uint16_t* Btw = (uint16_t*)((char*)d_ws + BT_OFF);
        float*    pts = (float*)((char*)d_ws + P_OFF);
        expand_a    <<<dim3(BATCH * 128 / 256), dim3(256), 0, stream>>>(x, idx, Aws);
        transpose_bt<<<dim3((KTOT / 64) * (SIZE_OUT / 64)), dim3(256), 0, stream>>>(table, Btw);
        gemm_splitq <<<dim3((BATCH / TM) * NUM_Q), dim3(512), 0, stream>>>(Aws, Btw, pts);
        reduce_ws   <<<dim3(BATCH * SIZE_OUT / 4 / 256), dim3(256), 0, stream>>>(pts, bias, out);
    } else {
        fallback_gather<<<dim3(BATCH), dim3(256), 0, stream>>>(x, idx, table, bias, out);
    }
}

// Round 8
// 97.328 us; speedup vs baseline: 1.0350x; 1.0350x over previous
//
#include <hip/hip_runtime.h>
#include <stdint.h>

// IndexedLinearLayer = dense bf16 GEMM, 3-kernel pipeline:
//   K1: Bt[o][k] = bf16(table[k][o])          (transpose, 8 MB in ws)
//   K2: per-(bt,q) block: mask x tile in-LDS -> A' (bf16), stream Bt chunk,
//       MFMA 16x16x32, write split-q partials to ws
//   K3: reduce 16 partials + bias -> out
//
// R8 = R7 resubmitted verbatim. R7 died to "container failed twice" with no
// compile/correctness signal; source audit shows all addressing in-bounds
// and no construct absent from the R3/R6 kernels that ran. R4/R5/R7 deaths
// vs R0-R3/R6 successes show no source correlation (R6 introduced no fix —
// the global_load_lds theory is falsified by R7 dying without it).
//
// R7 vs R6: expand_a fused into the GEMM (in-LDS mask+pack of the 256 KB
// x/idx tile) — R6's 4-node graph cost ~+10 µs vs R3's 2-node graph with
// MORE kernel work, so graph-node count/serialization is the active knob,
// not kernel-side FLOPs. Traffic delta: -23 MB expand ws I/O, +48 MB x/idx
// re-reads (L2-resident), net neutral; one fewer dependency edge.

constexpr int SIZE_IN  = 1024;
constexpr int SIZE_OUT = 256;
constexpr int BATCH    = 512;
constexpr int NUM_Q    = 16;
constexpr int KTOT     = NUM_Q * SIZE_IN;   // 16384
constexpr int A_LD     = 1040;              // bf16 elems/row in LDS (+16 pad)
constexpr int TM       = 32;                // batch tile

// ws layout (bytes)
constexpr size_t BT_OFF   = 0;
constexpr size_t BT_BYTES = (size_t)SIZE_OUT * KTOT * 2;            // 8,388,608
constexpr size_t P_OFF    = BT_OFF + BT_BYTES;
constexpr size_t P_BYTES  = (size_t)NUM_Q * BATCH * SIZE_OUT * 4;   // 8,388,608
constexpr size_t WS_NEED  = P_OFF + P_BYTES;                        // 16 MB

typedef short short8   __attribute__((ext_vector_type(8)));
typedef float floatx4  __attribute__((ext_vector_type(4)));

__device__ inline uint32_t pack2bf(float lo, float hi) {
    uint32_t a = __float_as_uint(lo) + 0x8000u;
    uint32_t b = __float_as_uint(hi) + 0x8000u;
    return __builtin_amdgcn_perm(b, a, 0x07060302);  // {b.hi16, a.hi16}
}
__device__ inline uint16_t bf1(float f) {
    return (uint16_t)((__float_as_uint(f) + 0x8000u) >> 16);
}

// ---- K1: Bt[o][k] = bf16(table[k][o]), 64x64 tiles through LDS ----
__global__ __launch_bounds__(256)
void transpose_bt(const float* __restrict__ table, uint16_t* __restrict__ Bt)
{
    __shared__ uint16_t t[64][72];                   // +8 pad
    const int k0  = (blockIdx.x & 255) * 64;
    const int o0  = (blockIdx.x >> 8) * 64;
    const int tid = threadIdx.x;
    {
        const int kr = tid >> 4;                     // 0..15
        const int oc = (tid & 15) * 4;
        #pragma unroll
        for (int rr = 0; rr < 4; ++rr) {
            const int k = rr * 16 + kr;
            const float4 v = *(const float4*)(table + (size_t)(k0 + k) * SIZE_OUT + o0 + oc);
            t[oc + 0][k] = bf1(v.x);
            t[oc + 1][k] = bf1(v.y);
            t[oc + 2][k] = bf1(v.z);
            t[oc + 3][k] = bf1(v.w);
        }
    }
    __syncthreads();
    const int orow = tid >> 2;                       // 0..63
    const int kc   = (tid & 3) * 16;
    const uint4 lo = *(const uint4*)(&t[orow][kc]);
    const uint4 hi = *(const uint4*)(&t[orow][kc + 8]);
    uint16_t* dst = Bt + (size_t)(o0 + orow) * KTOT + k0 + kc;
    *(uint4*)dst       = lo;
    *(uint4*)(dst + 8) = hi;
}

// ---- K2: fused mask + split-q GEMM. Block=(bt,q); 512 thr = 8 waves ----
__global__ __launch_bounds__(512, 1)
void gemm_fused(const float* __restrict__ x,        // [512,1024]
                const int*   __restrict__ idx,      // [512,1024]
                const uint16_t* __restrict__ Bt,    // [256][16384]
                float* __restrict__ parts)          // [16][512][256]
{
    __shared__ uint16_t Al[TM * A_LD];              // 66,560 B
    const int tid   = threadIdx.x;
    const int q     = blockIdx.x & 15;              // XCD = blockIdx%8 = q%8
    const int bt    = blockIdx.x >> 4;
    const int b0    = bt * TM;
    const int w     = tid >> 6;
    const int lane  = tid & 63;
    const int nlane = lane & 15;
    const int quad  = lane >> 4;

    // Stage masked-x A-tile into LDS (bf16). Thread covers row s=tid>>4,
    // float4-chunks c = (tid&15), +16, ... (16 chunks); writes 8 B each.
    {
        const float4* x4 = (const float4*)(x   + b0 * SIZE_IN);
        const int4*   i4 = (const int4*)(idx + b0 * SIZE_IN);
        const int s  = tid >> 4;
        const int c0 = tid & 15;
        #pragma unroll 4
        for (int c = c0; c < 256; c += 16) {
            const float4 xv = x4[s * 256 + c];
            const int4   iv = i4[s * 256 + c];
            const float v0 = (iv.x == q) ? xv.x : 0.f;
            const float v1 = (iv.y == q) ? xv.y : 0.f;
            const float v2 = (iv.z == q) ? xv.z : 0.f;
            const float v3 = (iv.w == q) ? xv.w : 0.f;
            uint2 d;
            d.x = pack2bf(v0, v1);
            d.y = pack2bf(v2, v3);
            *(uint2*)(&Al[s * A_LD + c * 4]) = d;
        }
    }
    __syncthreads();

    const uint16_t* bp0 = Bt + (size_t)(w * 32 + nlane) * KTOT + q * SIZE_IN + quad * 8;
    const uint16_t* bp1 = bp0 + (size_t)16 * KTOT;
    const uint16_t* ar0 = Al + nlane * A_LD + quad * 8;
    const uint16_t* ar1 = ar0 + 16 * A_LD;

    floatx4 acc00 = {0,0,0,0}, acc01 = {0,0,0,0}, acc10 = {0,0,0,0}, acc11 = {0,0,0,0};

    #pragma unroll 8
    for (int kb = 0; kb < 32; ++kb) {
        const short8 a0 = *(const short8*)(ar0 + kb * 32);   // ds_read_b128
        const short8 a1 = *(const short8*)(ar1 + kb * 32);
        const short8 bq0 = *(const short8*)(bp0 + kb * 32);  // global dwordx4
        const short8 bq1 = *(const short8*)(bp1 + kb * 32);
        acc00 = __builtin_amdgcn_mfma_f32_16x16x32_bf16(a0, bq0, acc00, 0, 0, 0);
        acc10 = __builtin_amdgcn_mfma_f32_16x16x32_bf16(a1, bq0, acc10, 0, 0, 0);
        acc01 = __builtin_amdgcn_mfma_f32_16x16x32_bf16(a0, bq1, acc01, 0, 0, 0);
        acc11 = __builtin_amdgcn_mfma_f32_16x16x32_bf16(a1, bq1, acc11, 0, 0, 0);
    }

    // C/D layout: col = lane&15, row = quad*4 + reg
    float* pq = parts + ((size_t)q * BATCH + b0) * SIZE_OUT;
    const int col0 = w * 32 + nlane;
    #pragma unroll
    for (int rr = 0; rr < 4; ++rr) {
        const int r0 = quad * 4 + rr;
        pq[(size_t)r0 * SIZE_OUT + col0]            = acc00[rr];
        pq[(size_t)r0 * SIZE_OUT + col0 + 16]       = acc01[rr];
        pq[(size_t)(r0 + 16) * SIZE_OUT + col0]     = acc10[rr];
        pq[(size_t)(r0 + 16) * SIZE_OUT + col0 + 16]= acc11[rr];
    }
}

// ---- K3: sum 16 q-partials + bias ----
__global__ __launch_bounds__(256)
void reduce_ws(const float* __restrict__ ws, const float* __restrict__ bias,
               float* __restrict__ out)
{
    const int e  = blockIdx.x * 256 + threadIdx.x;      // 0..32767 float4s
    const int o4 = e & 63;
    const float4* w4 = reinterpret_cast<const float4*>(ws);
    float4 s = reinterpret_cast<const float4*>(bias)[o4];
    #pragma unroll
    for (int q = 0; q < NUM_Q; ++q) {
        const float4 v = w4[(size_t)q * (BATCH * SIZE_OUT / 4) + e];
        s.x += v.x; s.y += v.y; s.z += v.z; s.w += v.w;
    }
    reinterpret_cast<float4*>(out)[e] = s;
}

// ---- Fallback (ws too small): simple per-row gather (known-correct) ----
__global__ __launch_bounds__(256)
void fallback_gather(const float* __restrict__ x, const int* __restrict__ idx,
                     const float* __restrict__ table, const float* __restrict__ bias,
                     float* __restrict__ out)
{
    __shared__ int2 xr[SIZE_IN];
    const int b = blockIdx.x, tid = threadIdx.x;
    const float4 xv = reinterpret_cast<const float4*>(x + b * SIZE_IN)[tid];
    const int4   qv = reinterpret_cast<const int4*>(idx + b * SIZE_IN)[tid];
    const int ib = tid * 4;
    xr[ib+0] = make_int2(__float_as_int(xv.x), (qv.x*SIZE_IN+ib+0)*SIZE_OUT);
    xr[ib+1] = make_int2(__float_as_int(xv.y), (qv.y*SIZE_IN+ib+1)*SIZE_OUT);
    xr[ib+2] = make_int2(__float_as_int(xv.z), (qv.z*SIZE_IN+ib+2)*SIZE_OUT);
    xr[ib+3] = make_int2(__float_as_int(xv.w), (qv.w*SIZE_IN+ib+3)*SIZE_OUT);
    __syncthreads();
    float s = bias[tid];
    for (int j = 0; j < SIZE_IN; ++j) {
        const int2 p = xr[j];
        s = fmaf(__int_as_float(p.x), table[p.y + tid], s);
    }
    out[b * SIZE_OUT + tid] = s;
}

extern "C" void kernel_launch(void* const* d_in, const int* in_sizes, int n_in,
                              void* d_out, int out_size, void* d_ws, size_t ws_size,
                              hipStream_t stream) {
    const float* x     = (const float*)d_in[0];
    const int*   idx   = (const int*)d_in[1];
    const float* table = (const float*)d_in[2];
    const float* bias  = (const float*)d_in[3];
    float*       out   = (float*)d_out;

    if (ws_size >= WS_NEED) {
        uint16_t* Btw = (uint16_t*)((char*)d_ws + BT_OFF);
        float*    pts = (float*)((char*)d_ws + P_OFF);
        transpose_bt<<<dim3((KTOT / 64) * (SIZE_OUT / 64)), dim3(256), 0, stream>>>(table, Btw);
        gemm_fused  <<<dim3((BATCH / TM) * NUM_Q), dim3(512), 0, stream>>>(x, idx, Btw, pts);
        reduce_ws   <<<dim3(BATCH * SIZE_OUT / 4 / 256), dim3(256), 0, stream>>>(pts, bias, out);
    } else {
        fallback_gather<<<dim3(BATCH), dim3(256), 0, stream>>>(x, idx, table, bias, out);
    }
}

// Round 9
// 88.392 us; speedup vs baseline: 1.1396x; 1.1011x over previous
//
#include <hip/hip_runtime.h>
#include <stdint.h>

// IndexedLinearLayer as implicit-A GEMM, 2-kernel pipeline (R3 config —
// session-best 89.6 µs):
//   K1: per-(bt,nh,q) block: mask x tile in-LDS -> A' (bf16), read B (fp32)
//       scalar + pack bf16, MFMA 16x16x32, write split-q partials to ws
//   K2: reduce 16 partials + bias -> out
//
// R9 rationale: empirical node-count model over R1-R8:
//   dur ~= 90 µs floor + ~3.5 µs per graph node beyond 2; kernel-side work
//   is invisible (R1 gather ~40 µs, R3 scalar-GEMM ~30 µs, R8 tuned ~12 µs
//   all land at the same total once node count is equal). The floor is the
//   harness's two 256 MiB ws-poison fills (~43 µs each, top-5 every round).
//   Therefore: fewest nodes wins; revert to the measured-best 2-node R3.

constexpr int SIZE_IN  = 1024;
constexpr int SIZE_OUT = 256;
constexpr int BATCH    = 512;
constexpr int NUM_Q    = 16;
constexpr int TM = 32;             // batch tile
constexpr int TN = 128;            // out tile
constexpr int A_STRIDE = 1032;     // bf16 elems/row, +8 pad

constexpr size_t WS_NEED = (size_t)NUM_Q * BATCH * SIZE_OUT * sizeof(float); // 8 MB

typedef short short8   __attribute__((ext_vector_type(8)));
typedef float floatx4  __attribute__((ext_vector_type(4)));

__device__ inline uint32_t pack2bf(float lo, float hi) {
    uint32_t a = __float_as_uint(lo) + 0x8000u;
    uint32_t b = __float_as_uint(hi) + 0x8000u;
    return __builtin_amdgcn_perm(b, a, 0x07060302);  // {b.hi16, a.hi16}
}

template <bool USE_WS>
__global__ __launch_bounds__(256, 2)
void idxlin_mfma(const float* __restrict__ x,      // [512,1024]
                 const int*   __restrict__ idx,    // [512,1024]
                 const float* __restrict__ table,  // [16*1024, 256]
                 const float* __restrict__ bias,   // [256]
                 float*       __restrict__ out,    // [512,256] (atomic path: pre-zeroed)
                 float*       __restrict__ ws)     // [16,512,256] partials (ws path)
{
    __shared__ uint16_t Alds[TM * A_STRIDE];       // 66 KB -> 2 blocks/CU

    const int tid = threadIdx.x;
    const int q   = blockIdx.x & 15;               // XCD = blockIdx%8 = q%8
    const int r   = blockIdx.x >> 4;
    const int nh  = r & 1;
    const int bt  = r >> 1;
    const int b0  = bt * TM;
    const int n0  = nh * TN;

    // ---- Stage masked-x A-tile into LDS (bf16). Iter s fills row m=s. ----
    const float4* x4 = reinterpret_cast<const float4*>(x   + b0 * SIZE_IN);
    const int4*   i4 = reinterpret_cast<const int4*>(idx + b0 * SIZE_IN);
    #pragma unroll 4
    for (int s = 0; s < TM; ++s) {
        const int f = s * 256 + tid;
        const float4 xv = x4[f];
        const int4   iv = i4[f];
        const float v0 = (iv.x == q) ? xv.x : 0.f;
        const float v1 = (iv.y == q) ? xv.y : 0.f;
        const float v2 = (iv.z == q) ? xv.z : 0.f;
        const float v3 = (iv.w == q) ? xv.w : 0.f;
        uint2 d;
        d.x = pack2bf(v0, v1);
        d.y = pack2bf(v2, v3);
        *reinterpret_cast<uint2*>(&Alds[s * A_STRIDE + tid * 4]) = d;
    }
    __syncthreads();

    // ---- MFMA K-loop ----
    const int lane  = tid & 63;
    const int w     = tid >> 6;        // wave: owns out cols [n0+w*32, +32)
    const int nlane = lane & 15;
    const int quad  = lane >> 4;

    const float* bp = table + (q * SIZE_IN + quad * 8) * SIZE_OUT + n0 + w * 32 + nlane;
    const uint16_t* arow0 = &Alds[(0 * 16 + nlane) * A_STRIDE + quad * 8];
    const uint16_t* arow1 = &Alds[(1 * 16 + nlane) * A_STRIDE + quad * 8];

    floatx4 acc[2][2] = {{{0.f,0.f,0.f,0.f},{0.f,0.f,0.f,0.f}},
                         {{0.f,0.f,0.f,0.f},{0.f,0.f,0.f,0.f}}};

    #pragma unroll 2
    for (int kb = 0; kb < SIZE_IN / 32; ++kb) {
        float wv[2][8];
        #pragma unroll
        for (int nt = 0; nt < 2; ++nt)
            #pragma unroll
            for (int j = 0; j < 8; ++j)
                wv[nt][j] = bp[j * SIZE_OUT + nt * 16];

        const short8 a0 = *reinterpret_cast<const short8*>(arow0 + kb * 32);
        const short8 a1 = *reinterpret_cast<const short8*>(arow1 + kb * 32);

        #pragma unroll
        for (int nt = 0; nt < 2; ++nt) {
            union { uint32_t u[4]; short8 s; } bf;
            bf.u[0] = pack2bf(wv[nt][0], wv[nt][1]);
            bf.u[1] = pack2bf(wv[nt][2], wv[nt][3]);
            bf.u[2] = pack2bf(wv[nt][4], wv[nt][5]);
            bf.u[3] = pack2bf(wv[nt][6], wv[nt][7]);
            acc[0][nt] = __builtin_amdgcn_mfma_f32_16x16x32_bf16(a0, bf.s, acc[0][nt], 0, 0, 0);
            acc[1][nt] = __builtin_amdgcn_mfma_f32_16x16x32_bf16(a1, bf.s, acc[1][nt], 0, 0, 0);
        }
        bp += 32 * SIZE_OUT;
    }

    // ---- Split-K output. C/D layout: col = lane&15, row = quad*4 + reg ----
    if (USE_WS) {
        float* wsq = ws + ((size_t)(q * BATCH + b0)) * SIZE_OUT + n0;
        #pragma unroll
        for (int mt = 0; mt < 2; ++mt)
            #pragma unroll
            for (int nt = 0; nt < 2; ++nt)
                #pragma unroll
                for (int rr = 0; rr < 4; ++rr) {
                    const int row = mt * 16 + quad * 4 + rr;
                    const int col = w * 32 + nt * 16 + nlane;
                    wsq[row * SIZE_OUT + col] = acc[mt][nt][rr];
                }
    } else {
        #pragma unroll
        for (int mt = 0; mt < 2; ++mt)
            #pragma unroll
            for (int nt = 0; nt < 2; ++nt)
                #pragma unroll
                for (int rr = 0; rr < 4; ++rr) {
                    const int bg = b0 + mt * 16 + quad * 4 + rr;
                    const int o  = n0 + w * 32 + nt * 16 + nlane;
                    atomicAdd(&out[bg * SIZE_OUT + o], acc[mt][nt][rr]);
                }
        if (q == 0) {
            const int o_l = tid & (TN - 1);
            const int m0  = (tid >> 7) * 16;
            const float bv = bias[n0 + o_l];
            #pragma unroll
            for (int rr = 0; rr < 16; ++rr)
                atomicAdd(&out[(b0 + m0 + rr) * SIZE_OUT + n0 + o_l], bv);
        }
    }
}

// Sum 16 q-partials + bias. Flat float4 index e over [512 b][64 o4].
__global__ __launch_bounds__(256)
void reduce_ws(const float* __restrict__ ws, const float* __restrict__ bias,
               float* __restrict__ out)
{
    const int e  = blockIdx.x * 256 + threadIdx.x;      // 0..32767
    const int o4 = e & 63;
    const float4* w4 = reinterpret_cast<const float4*>(ws);
    float4 s = reinterpret_cast<const float4*>(bias)[o4];
    #pragma unroll
    for (int q = 0; q < NUM_Q; ++q) {
        const float4 v = w4[(size_t)q * (BATCH * SIZE_OUT / 4) + e];
        s.x += v.x; s.y += v.y; s.z += v.z; s.w += v.w;
    }
    reinterpret_cast<float4*>(out)[e] = s;
}

extern "C" void kernel_launch(void* const* d_in, const int* in_sizes, int n_in,
                              void* d_out, int out_size, void* d_ws, size_t ws_size,
                              hipStream_t stream) {
    const float* x     = (const float*)d_in[0];
    const int*   idx   = (const int*)d_in[1];
    const float* table = (const float*)d_in[2];
    const float* bias  = (const float*)d_in[3];
    float*       out   = (float*)d_out;
    float*       ws    = (float*)d_ws;

    if (ws_size >= WS_NEED) {
        idxlin_mfma<true><<<dim3(512), dim3(256), 0, stream>>>(x, idx, table, bias, out, ws);
        reduce_ws<<<dim3(BATCH * SIZE_OUT / 4 / 256), dim3(256), 0, stream>>>(ws, bias, out);
    } else {
        hipMemsetAsync(out, 0, (size_t)out_size * sizeof(float), stream);
        idxlin_mfma<false><<<dim3(512), dim3(256), 0, stream>>>(x, idx, table, bias, out, ws);
    }
}